// Round 1
// baseline (1871.648 us; speedup 1.0000x reference)
//
#include <hip/hip_runtime.h>
#include <math.h>

// Problem constants
#define DIMC 256   // input channels
#define NCH  176   // 128 q + 16 k + 32 v output channels
#define MM   1024  // N2 spatial
#define BB   16    // batch
#define KD   16    // DIM_K
#define HH   8     // heads
#define VD   32    // DIM_V
#define EPSV 1e-5

// ---------------------------------------------------------------------------
// K1: complex 1x1 conv ("projection"): O[b][o][m] = sum_c W[o][c] * X[b][c][m]
// o-tile 16, m-tile 256, c staged in chunks of 32 in LDS.
// ---------------------------------------------------------------------------
__global__ __launch_bounds__(256) void k_proj(
    const float* __restrict__ x_re, const float* __restrict__ x_im,
    const float* __restrict__ wq_re, const float* __restrict__ wq_im,
    const float* __restrict__ wk_re, const float* __restrict__ wk_im,
    const float* __restrict__ wv_re, const float* __restrict__ wv_im,
    float2* __restrict__ O)
{
    const int mt  = blockIdx.x;   // 0..3
    const int ot  = blockIdx.y;   // 0..10
    const int b   = blockIdx.z;   // 0..15
    const int tid = threadIdx.x;
    const int m0  = mt * 256;

    __shared__ __align__(16) float2 Xs[32][256];
    __shared__ __align__(16) float2 Ws[32][16];   // [c][o], float4-readable o-pairs

    float accr[16], acci[16];
#pragma unroll
    for (int i = 0; i < 16; ++i) { accr[i] = 0.f; acci[i] = 0.f; }

    for (int cc = 0; cc < DIMC; cc += 32) {
        // stage X chunk (32 c x 256 m), coalesced over m
#pragma unroll 4
        for (int i = 0; i < 32; ++i) {
            size_t g = ((size_t)(b * DIMC + cc + i)) * MM + m0 + tid;
            Xs[i][tid] = make_float2(x_re[g], x_im[g]);
        }
        // stage W chunk (32 c x 16 o)
#pragma unroll
        for (int i = 0; i < 2; ++i) {
            int idx = i * 256 + tid;      // 0..511
            int c  = idx >> 4;            // 0..31
            int ol = idx & 15;
            int o  = ot * 16 + ol;
            int cg = cc + c;
            float wr, wi;
            if (o < 128)      { wr = wq_re[o * DIMC + cg];         wi = wq_im[o * DIMC + cg]; }
            else if (o < 144) { wr = wk_re[(o - 128) * DIMC + cg]; wi = wk_im[(o - 128) * DIMC + cg]; }
            else              { wr = wv_re[(o - 144) * DIMC + cg]; wi = wv_im[(o - 144) * DIMC + cg]; }
            Ws[c][ol] = make_float2(wr, wi);
        }
        __syncthreads();

        for (int c = 0; c < 32; ++c) {
            float2 xv = Xs[c][tid];
#pragma unroll
            for (int o2 = 0; o2 < 8; ++o2) {
                float4 w = *(const float4*)&Ws[c][o2 * 2];   // broadcast read
                accr[o2*2]     += w.x * xv.x - w.y * xv.y;
                acci[o2*2]     += w.x * xv.y + w.y * xv.x;
                accr[o2*2 + 1] += w.z * xv.x - w.w * xv.y;
                acci[o2*2 + 1] += w.z * xv.y + w.w * xv.x;
            }
        }
        __syncthreads();
    }

#pragma unroll
    for (int ol = 0; ol < 16; ++ol) {
        int o = ot * 16 + ol;
        O[((size_t)(b * NCH + o)) * MM + m0 + tid] = make_float2(accr[ol], acci[ol]);
    }
}

// ---------------------------------------------------------------------------
// K2: complex BN stats per channel (q: 128 ch, v: 32 ch), double accumulation.
// var = E[x^2] - mean^2 (complex square!) -- near-cancellation, needs care.
// Emits affine transform A,B with x -> A*x + B  (A = scale/sqrt(var+eps),
// B = shift - A*mean), folding the complex sqrt + divide.
// ---------------------------------------------------------------------------
__global__ __launch_bounds__(256) void k_bnstats(
    const float2* __restrict__ O,
    const float* __restrict__ qs_re, const float* __restrict__ qs_im,
    const float* __restrict__ qb_re, const float* __restrict__ qb_im,
    const float* __restrict__ vs_re, const float* __restrict__ vs_im,
    const float* __restrict__ vb_re, const float* __restrict__ vb_im,
    float4* __restrict__ stats)
{
    const int ch  = blockIdx.x;                    // 0..159
    const int o   = (ch < 128) ? ch : (144 + ch - 128);
    const int tid = threadIdx.x;

    double sr = 0, si = 0, sq = 0, sri = 0;        // sum r, i, r^2-i^2, r*i
    for (int idx = tid; idx < BB * MM; idx += 256) {
        int b = idx >> 10, m = idx & 1023;
        float2 val = O[((size_t)(b * NCH + o)) * MM + m];
        double r = val.x, ii = val.y;
        sr += r; si += ii; sq += r * r - ii * ii; sri += r * ii;
    }
    __shared__ double red[4][256];
    red[0][tid] = sr; red[1][tid] = si; red[2][tid] = sq; red[3][tid] = sri;
    __syncthreads();
    for (int s = 128; s > 0; s >>= 1) {
        if (tid < s) {
            red[0][tid] += red[0][tid + s]; red[1][tid] += red[1][tid + s];
            red[2][tid] += red[2][tid + s]; red[3][tid] += red[3][tid + s];
        }
        __syncthreads();
    }
    if (tid == 0) {
        const double inv = 1.0 / (double)(BB * MM);
        double mr = red[0][0] * inv, mi = red[1][0] * inv;
        double vr = red[2][0] * inv - (mr * mr - mi * mi) + EPSV;  // + real eps
        double vi = 2.0 * (red[3][0] * inv - mr * mi);
        // principal complex sqrt
        double rad = sqrt(vr * vr + vi * vi);
        double wr  = sqrt(fmax(0.5 * (rad + vr), 0.0));
        double wi  = sqrt(fmax(0.5 * (rad - vr), 0.0));
        if (vi < 0) wi = -wi;
        double den = wr * wr + wi * wi;
        double ivr = wr / den, ivi = -wi / den;    // 1/sqrt(var+eps)
        double scr, sci, shr, shi;
        if (ch < 128) { scr = qs_re[ch]; sci = qs_im[ch]; shr = qb_re[ch]; shi = qb_im[ch]; }
        else { int i2 = ch - 128; scr = vs_re[i2]; sci = vs_im[i2]; shr = vb_re[i2]; shi = vb_im[i2]; }
        double Ar = scr * ivr - sci * ivi;
        double Ai = scr * ivi + sci * ivr;
        double Br = shr - (Ar * mr - Ai * mi);
        double Bi = shi - (Ar * mi + Ai * mr);
        stats[ch] = make_float4((float)Ar, (float)Ai, (float)Br, (float)Bi);
    }
}

// ---------------------------------------------------------------------------
// K3a: apply BN affine in place to the q and v planes
// ---------------------------------------------------------------------------
__global__ __launch_bounds__(256) void k_bnapply(
    const float4* __restrict__ stats, float2* __restrict__ O)
{
    int ch = blockIdx.x, b = blockIdx.y;
    int o  = (ch < 128) ? ch : (144 + ch - 128);
    float4 s = stats[ch];
    float2* row = O + ((size_t)(b * NCH + o)) * MM;
    for (int m = threadIdx.x; m < MM; m += 256) {
        float2 v = row[m];
        row[m] = make_float2(s.x * v.x - s.y * v.y + s.z,
                             s.x * v.y + s.y * v.x + s.w);
    }
}

// ---------------------------------------------------------------------------
// K3b: softmax over m of |k| per (b, k-channel); k rows are NOT batch-normed.
// ---------------------------------------------------------------------------
__global__ __launch_bounds__(256) void k_softmax(
    const float2* __restrict__ O, float* __restrict__ sk)
{
    int kc = blockIdx.x, b = blockIdx.y;
    const float2* row = O + ((size_t)(b * NCH + 128 + kc)) * MM;
    int tid = threadIdx.x;
    float mag[4];
    float mx = -1e30f;
#pragma unroll
    for (int j = 0; j < 4; ++j) {
        float2 v = row[tid + j * 256];
        mag[j] = sqrtf(v.x * v.x + v.y * v.y);
        mx = fmaxf(mx, mag[j]);
    }
    __shared__ float red[256];
    red[tid] = mx; __syncthreads();
    for (int s = 128; s > 0; s >>= 1) { if (tid < s) red[tid] = fmaxf(red[tid], red[tid + s]); __syncthreads(); }
    mx = red[0]; __syncthreads();
    float e[4]; float sum = 0.f;
#pragma unroll
    for (int j = 0; j < 4; ++j) { e[j] = expf(mag[j] - mx); sum += e[j]; }
    red[tid] = sum; __syncthreads();
    for (int s = 128; s > 0; s >>= 1) { if (tid < s) red[tid] += red[tid + s]; __syncthreads(); }
    float inv = 1.f / red[0];
    float* outp = sk + ((size_t)(b * KD + kc)) * MM;
#pragma unroll
    for (int j = 0; j < 4; ++j) outp[tid + j * 256] = e[j] * inv;
}

// ---------------------------------------------------------------------------
// K5: content lambda  lam_c[b][k][v] = sum_m sk[b,k,m] * Vn[b,v,m]
// ---------------------------------------------------------------------------
__global__ __launch_bounds__(256) void k_lamc(
    const float2* __restrict__ O, const float* __restrict__ sk,
    float2* __restrict__ lamc)
{
    int k = blockIdx.x, b = blockIdx.y;
    int tid = threadIdx.x;
    int v = tid >> 3, s = tid & 7;
    const float*  skr  = sk + ((size_t)(b * KD + k)) * MM;
    const float2* vrow = O  + ((size_t)(b * NCH + 144 + v)) * MM;
    float ar = 0.f, ai = 0.f;
    for (int i = 0; i < 128; ++i) {
        int m = s * 128 + i;
        float w = skr[m]; float2 vv = vrow[m];
        ar += w * vv.x; ai += w * vv.y;
    }
    __shared__ float2 part[32][8];
    part[v][s] = make_float2(ar, ai);
    __syncthreads();
    if (tid < 32) {
        float2 t = part[tid][0];
#pragma unroll
        for (int j = 1; j < 8; ++j) { t.x += part[tid][j].x; t.y += part[tid][j].y; }
        lamc[((size_t)(b * KD + k)) * VD + tid] = t;
    }
}

// ---------------------------------------------------------------------------
// K6: the big fused kernel. Block = (b, n-tile of 8).
// lam_p[n,k,v] = sum_m emb[mi-ni+31, mj-nj+31, k] * Vn[b,v,m]   (complex)
// Y[b,h,v,n]  = sum_k Qn[b,h*16+k,n] * (lam_c[b,k,v] + lam_p[n,k,v])
// Thread tiling: 8 vt x 4 kt x 8 nl; each thread owns a 4k x 4v complex acc.
// m staged in chunks of 32 (one emb row: di constant, dj contiguous).
// ---------------------------------------------------------------------------
__global__ __launch_bounds__(256, 3) void k_main(
    const float2* __restrict__ O,
    const float* __restrict__ emb_re, const float* __restrict__ emb_im,
    const float2* __restrict__ lamc, float* __restrict__ out, int cplx)
{
    const int nt  = blockIdx.x;   // 0..127
    const int b   = blockIdx.y;   // 0..15
    const int tid = threadIdx.x;
    const int n0  = nt * 8;
    const int ni  = n0 >> 5;      // constant over the tile (8 | 32)
    const int nj0 = n0 & 31;

    __shared__ __align__(16) float2 Rs[8][32][16];  // [n][m][k]; reused as lam[8][16][32]
    __shared__ __align__(16) float2 Vs[32][34];     // [m][v], padded to even f2 for b128
    __shared__ __align__(16) float2 Qs[128][8];     // [o][n]

    // stage q tile (BN already applied in place)
#pragma unroll
    for (int i = 0; i < 4; ++i) {
        int idx = i * 256 + tid;          // 0..1023
        int o = idx >> 3, nl2 = idx & 7;
        Qs[o][nl2] = O[((size_t)(b * NCH + o)) * MM + n0 + nl2];
    }

    const int vt = tid & 7, kt = (tid >> 3) & 3, nl = tid >> 5;
    const int k0 = kt * 4, v0 = vt * 4;

    float ar[4][4], ai[4][4];
#pragma unroll
    for (int a = 0; a < 4; ++a)
#pragma unroll
        for (int c = 0; c < 4; ++c) { ar[a][c] = 0.f; ai[a][c] = 0.f; }

    for (int m0 = 0; m0 < MM; m0 += 32) {
        const int di = (m0 >> 5) - ni + 31;
        // stage R: gather emb -> Rs[n][m][k]; wave reads 1KB contiguous (k,dj fast)
#pragma unroll 4
        for (int i = 0; i < 16; ++i) {
            int idx = i * 256 + tid;          // 0..4095
            int kk = idx & 15;
            int ml = (idx >> 4) & 31;
            int nn = idx >> 9;                // 0..7
            int dj = ml - (nj0 + nn) + 31;    // in [0,62]
            int e  = (di * 63 + dj) * 16 + kk;
            Rs[nn][ml][kk] = make_float2(emb_re[e], emb_im[e]);
        }
        // stage V chunk (coalesced over m)
#pragma unroll
        for (int i = 0; i < 4; ++i) {
            int idx = i * 256 + tid;          // 0..1023
            int ml = idx & 31, vv = idx >> 5;
            Vs[ml][vv] = O[((size_t)(b * NCH + 144 + vv)) * MM + m0 + ml];
        }
        __syncthreads();

#pragma unroll 4
        for (int ml = 0; ml < 32; ++ml) {
            float4 r01 = *(const float4*)&Rs[nl][ml][k0];
            float4 r23 = *(const float4*)&Rs[nl][ml][k0 + 2];
            float4 v01 = *(const float4*)&Vs[ml][v0];
            float4 v23 = *(const float4*)&Vs[ml][v0 + 2];
            float rr[4] = { r01.x, r01.z, r23.x, r23.z };
            float rim[4] = { r01.y, r01.w, r23.y, r23.w };
            float vr[4] = { v01.x, v01.z, v23.x, v23.z };
            float vi[4] = { v01.y, v01.w, v23.y, v23.w };
#pragma unroll
            for (int a = 0; a < 4; ++a)
#pragma unroll
                for (int c = 0; c < 4; ++c) {
                    ar[a][c] += rr[a] * vr[c] - rim[a] * vi[c];
                    ai[a][c] += rr[a] * vi[c] + rim[a] * vr[c];
                }
        }
        __syncthreads();
    }

    // epilogue: lam_total = lam_p + lam_c  -> LDS (reuse Rs region)
    float2* lams = (float2*)Rs;   // [8][16][32]
#pragma unroll
    for (int a = 0; a < 4; ++a)
#pragma unroll
        for (int c = 0; c < 4; ++c) {
            int kk = k0 + a, vv = v0 + c;
            float2 lc = lamc[((size_t)(b * KD + kk)) * VD + vv];
            lams[(nl * 16 + kk) * 32 + vv] = make_float2(ar[a][c] + lc.x, ai[a][c] + lc.y);
        }
    __syncthreads();

    // Y[b,h,v,n] = sum_k Qn * lam_total
    const int h = tid >> 5;
    const int vv2 = tid & 31;
    float yr[8], yi[8];
#pragma unroll
    for (int n2 = 0; n2 < 8; ++n2) {
        float sr = 0.f, si = 0.f;
#pragma unroll
        for (int k = 0; k < 16; ++k) {
            float2 q = Qs[h * 16 + k][n2];
            float2 l = lams[(n2 * 16 + k) * 32 + vv2];
            sr += q.x * l.x - q.y * l.y;
            si += q.x * l.y + q.y * l.x;
        }
        yr[n2] = sr; yi[n2] = si;
    }

    if (cplx) {
        float4* op = (float4*)(out + (((size_t)b * 256 + h * 32 + vv2) * MM + n0) * 2);
        op[0] = make_float4(yr[0], yi[0], yr[1], yi[1]);
        op[1] = make_float4(yr[2], yi[2], yr[3], yi[3]);
        op[2] = make_float4(yr[4], yi[4], yr[5], yi[5]);
        op[3] = make_float4(yr[6], yi[6], yr[7], yi[7]);
    } else {
        float4* op = (float4*)(out + ((size_t)b * 256 + h * 32 + vv2) * MM + n0);
        op[0] = make_float4(yr[0], yr[1], yr[2], yr[3]);
        op[1] = make_float4(yr[4], yr[5], yr[6], yr[7]);
    }
}

// ---------------------------------------------------------------------------
extern "C" void kernel_launch(void* const* d_in, const int* in_sizes, int n_in,
                              void* d_out, int out_size, void* d_ws, size_t ws_size,
                              hipStream_t stream)
{
    const float* x_re  = (const float*)d_in[0];
    const float* x_im  = (const float*)d_in[1];
    const float* wq_re = (const float*)d_in[2];
    const float* wq_im = (const float*)d_in[3];
    const float* wk_re = (const float*)d_in[4];
    const float* wk_im = (const float*)d_in[5];
    const float* wv_re = (const float*)d_in[6];
    const float* wv_im = (const float*)d_in[7];
    const float* qs_re = (const float*)d_in[8];
    const float* qs_im = (const float*)d_in[9];
    const float* qb_re = (const float*)d_in[10];
    const float* qb_im = (const float*)d_in[11];
    const float* vs_re = (const float*)d_in[12];
    const float* vs_im = (const float*)d_in[13];
    const float* vb_re = (const float*)d_in[14];
    const float* vb_im = (const float*)d_in[15];
    const float* emb_re = (const float*)d_in[16];
    const float* emb_im = (const float*)d_in[17];

    float* ws = (float*)d_ws;
    // workspace layout (floats):
    const size_t O_OFF    = 0;                         // 16*176*1024*2 = 5,767,168
    const size_t ST_OFF   = O_OFF + (size_t)BB * NCH * MM * 2;   // 160*4 = 640
    const size_t SK_OFF   = ST_OFF + 640;              // 16*16*1024 = 262,144
    const size_t LC_OFF   = SK_OFF + (size_t)BB * KD * MM;       // 16*16*32*2 = 16,384

    float2* O     = (float2*)(ws + O_OFF);
    float4* stats = (float4*)(ws + ST_OFF);
    float*  sk    = ws + SK_OFF;
    float2* lamc  = (float2*)(ws + LC_OFF);
    float*  outp  = (float*)d_out;

    int cplx = (out_size >= 2 * BB * 256 * MM) ? 1 : 0;

    k_proj<<<dim3(4, 11, BB), 256, 0, stream>>>(x_re, x_im, wq_re, wq_im,
                                                wk_re, wk_im, wv_re, wv_im, O);
    k_bnstats<<<dim3(160), 256, 0, stream>>>(O, qs_re, qs_im, qb_re, qb_im,
                                             vs_re, vs_im, vb_re, vb_im, stats);
    k_bnapply<<<dim3(160, BB), 256, 0, stream>>>(stats, O);
    k_softmax<<<dim3(KD, BB), 256, 0, stream>>>(O, sk);
    k_lamc<<<dim3(KD, BB), 256, 0, stream>>>(O, sk, lamc);
    k_main<<<dim3(128, BB), 256, 0, stream>>>(O, emb_re, emb_im, lamc, outp, cplx);
}

// Round 2
// 779.516 us; speedup vs baseline: 2.4010x; 2.4010x over previous
//
#include <hip/hip_runtime.h>
#include <math.h>

// Problem constants
#define DIMC 256   // input channels
#define NCH  176   // 128 q + 16 k + 32 v output channels
#define MM   1024  // N2 spatial
#define BB   16    // batch
#define KD   16    // DIM_K
#define HH   8     // heads
#define VD   32    // DIM_V
#define EPSV 1e-5

typedef short short8 __attribute__((ext_vector_type(8)));
typedef float f32x4  __attribute__((ext_vector_type(4)));
typedef unsigned u32x4v __attribute__((ext_vector_type(4)));
typedef u32x4v u32x4a __attribute__((aligned(4)));   // 4-byte-aligned dwordx4

__device__ __forceinline__ unsigned bf16rne(float f) {
    unsigned u = __float_as_uint(f);
    unsigned r = u + 0x7FFFu + ((u >> 16) & 1u);
    return r >> 16;
}

#define GL2LDS16(g, l) __builtin_amdgcn_global_load_lds( \
    (const __attribute__((address_space(1))) unsigned*)(g), \
    (__attribute__((address_space(3))) unsigned*)(l), 16, 0, 0)

// ---------------------------------------------------------------------------
// K1: complex 1x1 conv: O[b][o][m] = sum_c W[o][c] * X[b][c][m]   (unchanged)
// ---------------------------------------------------------------------------
__global__ __launch_bounds__(256) void k_proj(
    const float* __restrict__ x_re, const float* __restrict__ x_im,
    const float* __restrict__ wq_re, const float* __restrict__ wq_im,
    const float* __restrict__ wk_re, const float* __restrict__ wk_im,
    const float* __restrict__ wv_re, const float* __restrict__ wv_im,
    float2* __restrict__ O)
{
    const int mt  = blockIdx.x;
    const int ot  = blockIdx.y;
    const int b   = blockIdx.z;
    const int tid = threadIdx.x;
    const int m0  = mt * 256;

    __shared__ __align__(16) float2 Xs[32][256];
    __shared__ __align__(16) float2 Ws[32][16];

    float accr[16], acci[16];
#pragma unroll
    for (int i = 0; i < 16; ++i) { accr[i] = 0.f; acci[i] = 0.f; }

    for (int cc = 0; cc < DIMC; cc += 32) {
#pragma unroll 4
        for (int i = 0; i < 32; ++i) {
            size_t g = ((size_t)(b * DIMC + cc + i)) * MM + m0 + tid;
            Xs[i][tid] = make_float2(x_re[g], x_im[g]);
        }
#pragma unroll
        for (int i = 0; i < 2; ++i) {
            int idx = i * 256 + tid;
            int c  = idx >> 4;
            int ol = idx & 15;
            int o  = ot * 16 + ol;
            int cg = cc + c;
            float wr, wi;
            if (o < 128)      { wr = wq_re[o * DIMC + cg];         wi = wq_im[o * DIMC + cg]; }
            else if (o < 144) { wr = wk_re[(o - 128) * DIMC + cg]; wi = wk_im[(o - 128) * DIMC + cg]; }
            else              { wr = wv_re[(o - 144) * DIMC + cg]; wi = wv_im[(o - 144) * DIMC + cg]; }
            Ws[c][ol] = make_float2(wr, wi);
        }
        __syncthreads();

        for (int c = 0; c < 32; ++c) {
            float2 xv = Xs[c][tid];
#pragma unroll
            for (int o2 = 0; o2 < 8; ++o2) {
                float4 w = *(const float4*)&Ws[c][o2 * 2];
                accr[o2*2]     += w.x * xv.x - w.y * xv.y;
                acci[o2*2]     += w.x * xv.y + w.y * xv.x;
                accr[o2*2 + 1] += w.z * xv.x - w.w * xv.y;
                acci[o2*2 + 1] += w.z * xv.y + w.w * xv.x;
            }
        }
        __syncthreads();
    }

#pragma unroll
    for (int ol = 0; ol < 16; ++ol) {
        int o = ot * 16 + ol;
        O[((size_t)(b * NCH + o)) * MM + m0 + tid] = make_float2(accr[ol], acci[ol]);
    }
}

// ---------------------------------------------------------------------------
// K2: complex BN stats (double accumulation), folds to affine A,B  (unchanged)
// ---------------------------------------------------------------------------
__global__ __launch_bounds__(256) void k_bnstats(
    const float2* __restrict__ O,
    const float* __restrict__ qs_re, const float* __restrict__ qs_im,
    const float* __restrict__ qb_re, const float* __restrict__ qb_im,
    const float* __restrict__ vs_re, const float* __restrict__ vs_im,
    const float* __restrict__ vb_re, const float* __restrict__ vb_im,
    float4* __restrict__ stats)
{
    const int ch  = blockIdx.x;
    const int o   = (ch < 128) ? ch : (144 + ch - 128);
    const int tid = threadIdx.x;

    double sr = 0, si = 0, sq = 0, sri = 0;
    for (int idx = tid; idx < BB * MM; idx += 256) {
        int b = idx >> 10, m = idx & 1023;
        float2 val = O[((size_t)(b * NCH + o)) * MM + m];
        double r = val.x, ii = val.y;
        sr += r; si += ii; sq += r * r - ii * ii; sri += r * ii;
    }
    __shared__ double red[4][256];
    red[0][tid] = sr; red[1][tid] = si; red[2][tid] = sq; red[3][tid] = sri;
    __syncthreads();
    for (int s = 128; s > 0; s >>= 1) {
        if (tid < s) {
            red[0][tid] += red[0][tid + s]; red[1][tid] += red[1][tid + s];
            red[2][tid] += red[2][tid + s]; red[3][tid] += red[3][tid + s];
        }
        __syncthreads();
    }
    if (tid == 0) {
        const double inv = 1.0 / (double)(BB * MM);
        double mr = red[0][0] * inv, mi = red[1][0] * inv;
        double vr = red[2][0] * inv - (mr * mr - mi * mi) + EPSV;
        double vi = 2.0 * (red[3][0] * inv - mr * mi);
        double rad = sqrt(vr * vr + vi * vi);
        double wr  = sqrt(fmax(0.5 * (rad + vr), 0.0));
        double wi  = sqrt(fmax(0.5 * (rad - vr), 0.0));
        if (vi < 0) wi = -wi;
        double den = wr * wr + wi * wi;
        double ivr = wr / den, ivi = -wi / den;
        double scr, sci, shr, shi;
        if (ch < 128) { scr = qs_re[ch]; sci = qs_im[ch]; shr = qb_re[ch]; shi = qb_im[ch]; }
        else { int i2 = ch - 128; scr = vs_re[i2]; sci = vs_im[i2]; shr = vb_re[i2]; shi = vb_im[i2]; }
        double Ar = scr * ivr - sci * ivi;
        double Ai = scr * ivi + sci * ivr;
        double Br = shr - (Ar * mr - Ai * mi);
        double Bi = shi - (Ar * mi + Ai * mr);
        stats[ch] = make_float4((float)Ar, (float)Ai, (float)Br, (float)Bi);
    }
}

// ---------------------------------------------------------------------------
// K3a: apply BN affine in place  (unchanged)
// ---------------------------------------------------------------------------
__global__ __launch_bounds__(256) void k_bnapply(
    const float4* __restrict__ stats, float2* __restrict__ O)
{
    int ch = blockIdx.x, b = blockIdx.y;
    int o  = (ch < 128) ? ch : (144 + ch - 128);
    float4 s = stats[ch];
    float2* row = O + ((size_t)(b * NCH + o)) * MM;
    for (int m = threadIdx.x; m < MM; m += 256) {
        float2 v = row[m];
        row[m] = make_float2(s.x * v.x - s.y * v.y + s.z,
                             s.x * v.y + s.y * v.x + s.w);
    }
}

// ---------------------------------------------------------------------------
// K3b: softmax over m of |k|  (unchanged)
// ---------------------------------------------------------------------------
__global__ __launch_bounds__(256) void k_softmax(
    const float2* __restrict__ O, float* __restrict__ sk)
{
    int kc = blockIdx.x, b = blockIdx.y;
    const float2* row = O + ((size_t)(b * NCH + 128 + kc)) * MM;
    int tid = threadIdx.x;
    float mag[4];
    float mx = -1e30f;
#pragma unroll
    for (int j = 0; j < 4; ++j) {
        float2 v = row[tid + j * 256];
        mag[j] = sqrtf(v.x * v.x + v.y * v.y);
        mx = fmaxf(mx, mag[j]);
    }
    __shared__ float red[256];
    red[tid] = mx; __syncthreads();
    for (int s = 128; s > 0; s >>= 1) { if (tid < s) red[tid] = fmaxf(red[tid], red[tid + s]); __syncthreads(); }
    mx = red[0]; __syncthreads();
    float e[4]; float sum = 0.f;
#pragma unroll
    for (int j = 0; j < 4; ++j) { e[j] = expf(mag[j] - mx); sum += e[j]; }
    red[tid] = sum; __syncthreads();
    for (int s = 128; s > 0; s >>= 1) { if (tid < s) red[tid] += red[tid + s]; __syncthreads(); }
    float inv = 1.f / red[0];
    float* outp = sk + ((size_t)(b * KD + kc)) * MM;
#pragma unroll
    for (int j = 0; j < 4; ++j) outp[tid + j * 256] = e[j] * inv;
}

// ---------------------------------------------------------------------------
// K5: content lambda  (unchanged)
// ---------------------------------------------------------------------------
__global__ __launch_bounds__(256) void k_lamc(
    const float2* __restrict__ O, const float* __restrict__ sk,
    float2* __restrict__ lamc)
{
    int k = blockIdx.x, b = blockIdx.y;
    int tid = threadIdx.x;
    int v = tid >> 3, s = tid & 7;
    const float*  skr  = sk + ((size_t)(b * KD + k)) * MM;
    const float2* vrow = O  + ((size_t)(b * NCH + 144 + v)) * MM;
    float ar = 0.f, ai = 0.f;
    for (int i = 0; i < 128; ++i) {
        int m = s * 128 + i;
        float w = skr[m]; float2 vv = vrow[m];
        ar += w * vv.x; ai += w * vv.y;
    }
    __shared__ float2 part[32][8];
    part[v][s] = make_float2(ar, ai);
    __syncthreads();
    if (tid < 32) {
        float2 t = part[tid][0];
#pragma unroll
        for (int j = 1; j < 8; ++j) { t.x += part[tid][j].x; t.y += part[tid][j].y; }
        lamc[((size_t)(b * KD + k)) * VD + tid] = t;
    }
}

// ---------------------------------------------------------------------------
// NEW: k_eprep — repack emb into embC[k][di][dj] = u32( bf16(im)<<16 | bf16(re) )
// Transposed layout makes each lane's MFMA A-fragment 32 contiguous bytes.
// ---------------------------------------------------------------------------
__global__ __launch_bounds__(256) void k_eprep(
    const float* __restrict__ er, const float* __restrict__ ei,
    unsigned* __restrict__ embC)
{
    int i = blockIdx.x * 256 + threadIdx.x;
    if (i >= 63 * 63 * 16) return;
    int kk = i & 15;
    int rest = i >> 4;
    int dj = rest % 63;
    int di = rest / 63;
    embC[(kk * 63 + di) * 63 + dj] = bf16rne(er[i]) | (bf16rne(ei[i]) << 16);
}

// ---------------------------------------------------------------------------
// NEW: k_vprep — split BN'd V channels of O into bf16 planes VbfR/VbfI[bv][m]
// (bv = b*32+v, 512 rows x 1024 m; stored as u32 = 2 packed bf16 along m)
// ---------------------------------------------------------------------------
__global__ __launch_bounds__(256) void k_vprep(
    const float2* __restrict__ O,
    unsigned* __restrict__ VR, unsigned* __restrict__ VI)
{
    int t = blockIdx.x * 256 + threadIdx.x;       // 0..262143
    int bv = t >> 9, mdw = t & 511;
    int b = bv >> 5, v = bv & 31;
    const float2* src = O + ((size_t)(b * NCH + 144 + v)) * MM + mdw * 2;
    float2 a = src[0], c = src[1];
    VR[t] = bf16rne(a.x) | (bf16rne(c.x) << 16);
    VI[t] = bf16rne(a.y) | (bf16rne(c.y) << 16);
}

// ---------------------------------------------------------------------------
// NEW k_main: bf16 MFMA for lam_p, fused lam_c add + q-contraction epilogue.
// Grid: (256 n-groups of 4, 2 bv-halves). Block 256 thr = 4 waves.
// Per n: lam[16k x 256bv] = R_n[16k x 1024m] x V[1024m x 256bv] (complex,
// 4 MFMA per frag-pair, f32 accum). A-frags gathered direct from embC
// (2x dwordx4 + v_perm split). B staged in LDS via global_load_lds w=16.
// ---------------------------------------------------------------------------
__global__ __launch_bounds__(256, 2) void k_main(
    const float2* __restrict__ O,
    const unsigned* __restrict__ embC,
    const unsigned* __restrict__ VbfR,
    const unsigned* __restrict__ VbfI,
    const float2* __restrict__ lamc,
    float* __restrict__ out, int cplx)
{
    const int tid  = threadIdx.x;
    const int w    = tid >> 6;
    const int lane = tid & 63;
    const int quad = lane >> 4;
    const int col  = lane & 15;

    const int n0  = blockIdx.x * 4;
    const int bvh = blockIdx.y;
    const int b0  = bvh * 8;
    const int ni  = n0 >> 5;
    const int nj0 = n0 & 31;

    // LDS: vs = staged V chunk (2 planes x 256 rows x 16 dwords) = 32 KB,
    // reused as lamt[16k][256bv] float2 in epilogue. qsh = 32 KB.
    __shared__ __align__(16) unsigned shraw[8192];
    unsigned* vsR = shraw;
    unsigned* vsI = shraw + 4096;
    float2*   lamt = (float2*)shraw;
    __shared__ __align__(16) float2 qsh[4096];    // [bl(8)][ch(128)][g(4)]

    // stage q tile (BN already applied in place); consumed after barriers
#pragma unroll
    for (int it = 0; it < 16; ++it) {
        int idx = it * 256 + tid;
        int g = idx & 3, ch = (idx >> 2) & 127, bl = idx >> 9;
        qsh[idx] = O[((size_t)((b0 + bl) * NCH + ch)) * MM + n0 + g];
    }

    f32x4 accr[4][4], acci[4][4];
#pragma unroll
    for (int g = 0; g < 4; ++g)
#pragma unroll
        for (int t = 0; t < 4; ++t) {
            accr[g][t] = (f32x4){0.f, 0.f, 0.f, 0.f};
            acci[g][t] = (f32x4){0.f, 0.f, 0.f, 0.f};
        }

    const unsigned* vsrcR = VbfR + (size_t)(bvh * 256) * 512;
    const unsigned* vsrcI = VbfI + (size_t)(bvh * 256) * 512;
    const int rowLane = lane >> 2;          // 0..15
    const int moff    = (lane & 3) * 4;     // dword offset within row chunk

    for (int c = 0; c < 32; ++c) {
        // ---- stage V chunk: wave w stages rows [w*64, w*64+64), 16 rows/instr
        {
            const unsigned* gR = vsrcR + ((size_t)(w * 64 + rowLane)) * 512 + c * 16 + moff;
            const unsigned* gI = vsrcI + ((size_t)(w * 64 + rowLane)) * 512 + c * 16 + moff;
#pragma unroll
            for (int r16 = 0; r16 < 4; ++r16) {
                GL2LDS16(gR + (size_t)r16 * 16 * 512, vsR + w * 1024 + r16 * 256);
                GL2LDS16(gI + (size_t)r16 * 16 * 512, vsI + w * 1024 + r16 * 256);
            }
        }
        __syncthreads();

        // ---- hoist B-fragments (reused across 4 n)
        short8 Br[4], Bi[4];
#pragma unroll
        for (int t = 0; t < 4; ++t) {
            int rowb = w * 64 + t * 16 + col;
            Br[t] = *(const short8*)&vsR[rowb * 16 + quad * 4];
            Bi[t] = *(const short8*)&vsI[rowb * 16 + quad * 4];
        }

        const int di = c - ni + 31;           // in [0,62]
#pragma unroll
        for (int g = 0; g < 4; ++g) {
            int dj0 = quad * 8 + 31 - (nj0 + g);      // in [0,55]
            const unsigned* ap = embC + ((size_t)(col * 63 + di)) * 63 + dj0;
            u32x4a d0 = *(const u32x4a*)ap;
            u32x4a d1 = *(const u32x4a*)(ap + 4);
            union { unsigned u[4]; short8 s; } Rr, Ri, Rin;
            Rr.u[0] = __builtin_amdgcn_perm(d0.y, d0.x, 0x05040100u);
            Rr.u[1] = __builtin_amdgcn_perm(d0.w, d0.z, 0x05040100u);
            Rr.u[2] = __builtin_amdgcn_perm(d1.y, d1.x, 0x05040100u);
            Rr.u[3] = __builtin_amdgcn_perm(d1.w, d1.z, 0x05040100u);
            Ri.u[0] = __builtin_amdgcn_perm(d0.y, d0.x, 0x07060302u);
            Ri.u[1] = __builtin_amdgcn_perm(d0.w, d0.z, 0x07060302u);
            Ri.u[2] = __builtin_amdgcn_perm(d1.y, d1.x, 0x07060302u);
            Ri.u[3] = __builtin_amdgcn_perm(d1.w, d1.z, 0x07060302u);
            Rin.u[0] = Ri.u[0] ^ 0x80008000u;
            Rin.u[1] = Ri.u[1] ^ 0x80008000u;
            Rin.u[2] = Ri.u[2] ^ 0x80008000u;
            Rin.u[3] = Ri.u[3] ^ 0x80008000u;
#pragma unroll
            for (int t = 0; t < 4; ++t) {
                accr[g][t] = __builtin_amdgcn_mfma_f32_16x16x32_bf16(Rr.s,  Br[t], accr[g][t], 0, 0, 0);
                accr[g][t] = __builtin_amdgcn_mfma_f32_16x16x32_bf16(Rin.s, Bi[t], accr[g][t], 0, 0, 0);
                acci[g][t] = __builtin_amdgcn_mfma_f32_16x16x32_bf16(Rr.s,  Bi[t], acci[g][t], 0, 0, 0);
                acci[g][t] = __builtin_amdgcn_mfma_f32_16x16x32_bf16(Ri.s,  Br[t], acci[g][t], 0, 0, 0);
            }
        }
        __syncthreads();   // protect vs before next chunk's staging
    }

    // ---- epilogue: per n: lam_tot -> LDS, then Y = q . lam_tot
    const int blY = tid >> 5, vY = tid & 31;
    const int bY  = b0 + blY;
#pragma unroll 1
    for (int g = 0; g < 4; ++g) {
        __syncthreads();
        // write lam_p + lam_c into lamt[k][bv]
#pragma unroll
        for (int t = 0; t < 4; ++t) {
            int bvl = w * 64 + t * 16 + col;
            int b   = b0 + (bvl >> 5);
            int v   = bvl & 31;
#pragma unroll
            for (int r = 0; r < 4; ++r) {
                int k = quad * 4 + r;
                float2 lc = lamc[((size_t)(b * KD + k)) * VD + v];
                lamt[k * 256 + bvl] = make_float2(accr[g][t][r] + lc.x,
                                                  acci[g][t][r] + lc.y);
            }
        }
        __syncthreads();
        // Y[b,h,v,n] = sum_k q[b,h*16+k,n] * lam_tot[k, b*32+v]
        float yr[8], yi[8];
#pragma unroll
        for (int h = 0; h < 8; ++h) { yr[h] = 0.f; yi[h] = 0.f; }
        for (int k = 0; k < 16; ++k) {
            float2 l = lamt[k * 256 + tid];
#pragma unroll
            for (int h = 0; h < 8; ++h) {
                float2 q = qsh[(blY * 128 + h * 16 + k) * 4 + g];
                yr[h] += q.x * l.x - q.y * l.y;
                yi[h] += q.x * l.y + q.y * l.x;
            }
        }
        int n = n0 + g;
        if (cplx) {
            float2* op = (float2*)out;
#pragma unroll
            for (int h = 0; h < 8; ++h)
                op[((size_t)(bY * 256 + h * 32 + vY)) * MM + n] = make_float2(yr[h], yi[h]);
        } else {
#pragma unroll
            for (int h = 0; h < 8; ++h)
                out[((size_t)(bY * 256 + h * 32 + vY)) * MM + n] = yr[h];
        }
    }
}

// ---------------------------------------------------------------------------
extern "C" void kernel_launch(void* const* d_in, const int* in_sizes, int n_in,
                              void* d_out, int out_size, void* d_ws, size_t ws_size,
                              hipStream_t stream)
{
    const float* x_re  = (const float*)d_in[0];
    const float* x_im  = (const float*)d_in[1];
    const float* wq_re = (const float*)d_in[2];
    const float* wq_im = (const float*)d_in[3];
    const float* wk_re = (const float*)d_in[4];
    const float* wk_im = (const float*)d_in[5];
    const float* wv_re = (const float*)d_in[6];
    const float* wv_im = (const float*)d_in[7];
    const float* qs_re = (const float*)d_in[8];
    const float* qs_im = (const float*)d_in[9];
    const float* qb_re = (const float*)d_in[10];
    const float* qb_im = (const float*)d_in[11];
    const float* vs_re = (const float*)d_in[12];
    const float* vs_im = (const float*)d_in[13];
    const float* vb_re = (const float*)d_in[14];
    const float* vb_im = (const float*)d_in[15];
    const float* emb_re = (const float*)d_in[16];
    const float* emb_im = (const float*)d_in[17];

    float* ws = (float*)d_ws;
    // workspace layout (4-byte units):
    const size_t O_OFF  = 0;                                     // 5,767,168
    const size_t ST_OFF = O_OFF + (size_t)BB * NCH * MM * 2;     // 640
    const size_t SK_OFF = ST_OFF + 640;                          // 262,144
    const size_t LC_OFF = SK_OFF + (size_t)BB * KD * MM;         // 16,384
    const size_t EC_OFF = LC_OFF + 16384;                        // 63,504 (embC u32)
    const size_t VR_OFF = EC_OFF + 63504;                        // 262,144 (u32)
    const size_t VI_OFF = VR_OFF + 262144;                       // 262,144 (u32)

    float2*   O     = (float2*)(ws + O_OFF);
    float4*   stats = (float4*)(ws + ST_OFF);
    float*    sk    = ws + SK_OFF;
    float2*   lamc  = (float2*)(ws + LC_OFF);
    unsigned* embC  = (unsigned*)(ws + EC_OFF);
    unsigned* VbfR  = (unsigned*)(ws + VR_OFF);
    unsigned* VbfI  = (unsigned*)(ws + VI_OFF);
    float*    outp  = (float*)d_out;

    int cplx = (out_size >= 2 * BB * 256 * MM) ? 1 : 0;

    k_proj<<<dim3(4, 11, BB), 256, 0, stream>>>(x_re, x_im, wq_re, wq_im,
                                                wk_re, wk_im, wv_re, wv_im, O);
    k_eprep<<<dim3(249), 256, 0, stream>>>(emb_re, emb_im, embC);
    k_bnstats<<<dim3(160), 256, 0, stream>>>(O, qs_re, qs_im, qb_re, qb_im,
                                             vs_re, vs_im, vb_re, vb_im, stats);
    k_bnapply<<<dim3(160, BB), 256, 0, stream>>>(stats, O);
    k_softmax<<<dim3(KD, BB), 256, 0, stream>>>(O, sk);
    k_lamc<<<dim3(KD, BB), 256, 0, stream>>>(O, sk, lamc);
    k_vprep<<<dim3(1024), 256, 0, stream>>>(O, VbfR, VbfI);
    k_main<<<dim3(256, 2), 256, 0, stream>>>(O, embC, VbfR, VbfI, lamc, outp, cplx);
}

// Round 3
// 515.896 us; speedup vs baseline: 3.6280x; 1.5110x over previous
//
#include <hip/hip_runtime.h>
#include <math.h>

// Problem constants
#define DIMC 256   // input channels
#define NCH  176   // 128 q + 16 k + 32 v output channels
#define MM   1024  // N2 spatial
#define BB   16    // batch
#define KD   16    // DIM_K
#define HH   8     // heads
#define VD   32    // DIM_V
#define EPSV 1e-5

typedef short short8 __attribute__((ext_vector_type(8)));
typedef float f32x4  __attribute__((ext_vector_type(4)));
typedef unsigned u32x4v __attribute__((ext_vector_type(4)));
typedef u32x4v u32x4a __attribute__((aligned(4)));   // 4-byte-aligned dwordx4

__device__ __forceinline__ unsigned bf16rne(float f) {
    unsigned u = __float_as_uint(f);
    unsigned r = u + 0x7FFFu + ((u >> 16) & 1u);
    return r >> 16;
}

#define GL2LDS16(g, l) __builtin_amdgcn_global_load_lds( \
    (const __attribute__((address_space(1))) unsigned*)(g), \
    (__attribute__((address_space(3))) unsigned*)(l), 16, 0, 0)

// ---------------------------------------------------------------------------
// K1: complex 1x1 conv: O[b][o][m] = sum_c W[o][c] * X[b][c][m]   (unchanged)
// ---------------------------------------------------------------------------
__global__ __launch_bounds__(256) void k_proj(
    const float* __restrict__ x_re, const float* __restrict__ x_im,
    const float* __restrict__ wq_re, const float* __restrict__ wq_im,
    const float* __restrict__ wk_re, const float* __restrict__ wk_im,
    const float* __restrict__ wv_re, const float* __restrict__ wv_im,
    float2* __restrict__ O)
{
    const int mt  = blockIdx.x;
    const int ot  = blockIdx.y;
    const int b   = blockIdx.z;
    const int tid = threadIdx.x;
    const int m0  = mt * 256;

    __shared__ __align__(16) float2 Xs[32][256];
    __shared__ __align__(16) float2 Ws[32][16];

    float accr[16], acci[16];
#pragma unroll
    for (int i = 0; i < 16; ++i) { accr[i] = 0.f; acci[i] = 0.f; }

    for (int cc = 0; cc < DIMC; cc += 32) {
#pragma unroll 4
        for (int i = 0; i < 32; ++i) {
            size_t g = ((size_t)(b * DIMC + cc + i)) * MM + m0 + tid;
            Xs[i][tid] = make_float2(x_re[g], x_im[g]);
        }
#pragma unroll
        for (int i = 0; i < 2; ++i) {
            int idx = i * 256 + tid;
            int c  = idx >> 4;
            int ol = idx & 15;
            int o  = ot * 16 + ol;
            int cg = cc + c;
            float wr, wi;
            if (o < 128)      { wr = wq_re[o * DIMC + cg];         wi = wq_im[o * DIMC + cg]; }
            else if (o < 144) { wr = wk_re[(o - 128) * DIMC + cg]; wi = wk_im[(o - 128) * DIMC + cg]; }
            else              { wr = wv_re[(o - 144) * DIMC + cg]; wi = wv_im[(o - 144) * DIMC + cg]; }
            Ws[c][ol] = make_float2(wr, wi);
        }
        __syncthreads();

        for (int c = 0; c < 32; ++c) {
            float2 xv = Xs[c][tid];
#pragma unroll
            for (int o2 = 0; o2 < 8; ++o2) {
                float4 w = *(const float4*)&Ws[c][o2 * 2];
                accr[o2*2]     += w.x * xv.x - w.y * xv.y;
                acci[o2*2]     += w.x * xv.y + w.y * xv.x;
                accr[o2*2 + 1] += w.z * xv.x - w.w * xv.y;
                acci[o2*2 + 1] += w.z * xv.y + w.w * xv.x;
            }
        }
        __syncthreads();
    }

#pragma unroll
    for (int ol = 0; ol < 16; ++ol) {
        int o = ot * 16 + ol;
        O[((size_t)(b * NCH + o)) * MM + m0 + tid] = make_float2(accr[ol], acci[ol]);
    }
}

// ---------------------------------------------------------------------------
// K2: complex BN stats (double accumulation), folds to affine A,B  (unchanged)
// ---------------------------------------------------------------------------
__global__ __launch_bounds__(256) void k_bnstats(
    const float2* __restrict__ O,
    const float* __restrict__ qs_re, const float* __restrict__ qs_im,
    const float* __restrict__ qb_re, const float* __restrict__ qb_im,
    const float* __restrict__ vs_re, const float* __restrict__ vs_im,
    const float* __restrict__ vb_re, const float* __restrict__ vb_im,
    float4* __restrict__ stats)
{
    const int ch  = blockIdx.x;
    const int o   = (ch < 128) ? ch : (144 + ch - 128);
    const int tid = threadIdx.x;

    double sr = 0, si = 0, sq = 0, sri = 0;
    for (int idx = tid; idx < BB * MM; idx += 256) {
        int b = idx >> 10, m = idx & 1023;
        float2 val = O[((size_t)(b * NCH + o)) * MM + m];
        double r = val.x, ii = val.y;
        sr += r; si += ii; sq += r * r - ii * ii; sri += r * ii;
    }
    __shared__ double red[4][256];
    red[0][tid] = sr; red[1][tid] = si; red[2][tid] = sq; red[3][tid] = sri;
    __syncthreads();
    for (int s = 128; s > 0; s >>= 1) {
        if (tid < s) {
            red[0][tid] += red[0][tid + s]; red[1][tid] += red[1][tid + s];
            red[2][tid] += red[2][tid + s]; red[3][tid] += red[3][tid + s];
        }
        __syncthreads();
    }
    if (tid == 0) {
        const double inv = 1.0 / (double)(BB * MM);
        double mr = red[0][0] * inv, mi = red[1][0] * inv;
        double vr = red[2][0] * inv - (mr * mr - mi * mi) + EPSV;
        double vi = 2.0 * (red[3][0] * inv - mr * mi);
        double rad = sqrt(vr * vr + vi * vi);
        double wr  = sqrt(fmax(0.5 * (rad + vr), 0.0));
        double wi  = sqrt(fmax(0.5 * (rad - vr), 0.0));
        if (vi < 0) wi = -wi;
        double den = wr * wr + wi * wi;
        double ivr = wr / den, ivi = -wi / den;
        double scr, sci, shr, shi;
        if (ch < 128) { scr = qs_re[ch]; sci = qs_im[ch]; shr = qb_re[ch]; shi = qb_im[ch]; }
        else { int i2 = ch - 128; scr = vs_re[i2]; sci = vs_im[i2]; shr = vb_re[i2]; shi = vb_im[i2]; }
        double Ar = scr * ivr - sci * ivi;
        double Ai = scr * ivi + sci * ivr;
        double Br = shr - (Ar * mr - Ai * mi);
        double Bi = shi - (Ar * mi + Ai * mr);
        stats[ch] = make_float4((float)Ar, (float)Ai, (float)Br, (float)Bi);
    }
}

// ---------------------------------------------------------------------------
// K3a: apply BN affine in place  (unchanged)
// ---------------------------------------------------------------------------
__global__ __launch_bounds__(256) void k_bnapply(
    const float4* __restrict__ stats, float2* __restrict__ O)
{
    int ch = blockIdx.x, b = blockIdx.y;
    int o  = (ch < 128) ? ch : (144 + ch - 128);
    float4 s = stats[ch];
    float2* row = O + ((size_t)(b * NCH + o)) * MM;
    for (int m = threadIdx.x; m < MM; m += 256) {
        float2 v = row[m];
        row[m] = make_float2(s.x * v.x - s.y * v.y + s.z,
                             s.x * v.y + s.y * v.x + s.w);
    }
}

// ---------------------------------------------------------------------------
// K3b: softmax over m of |k|  (unchanged)
// ---------------------------------------------------------------------------
__global__ __launch_bounds__(256) void k_softmax(
    const float2* __restrict__ O, float* __restrict__ sk)
{
    int kc = blockIdx.x, b = blockIdx.y;
    const float2* row = O + ((size_t)(b * NCH + 128 + kc)) * MM;
    int tid = threadIdx.x;
    float mag[4];
    float mx = -1e30f;
#pragma unroll
    for (int j = 0; j < 4; ++j) {
        float2 v = row[tid + j * 256];
        mag[j] = sqrtf(v.x * v.x + v.y * v.y);
        mx = fmaxf(mx, mag[j]);
    }
    __shared__ float red[256];
    red[tid] = mx; __syncthreads();
    for (int s = 128; s > 0; s >>= 1) { if (tid < s) red[tid] = fmaxf(red[tid], red[tid + s]); __syncthreads(); }
    mx = red[0]; __syncthreads();
    float e[4]; float sum = 0.f;
#pragma unroll
    for (int j = 0; j < 4; ++j) { e[j] = expf(mag[j] - mx); sum += e[j]; }
    red[tid] = sum; __syncthreads();
    for (int s = 128; s > 0; s >>= 1) { if (tid < s) red[tid] += red[tid + s]; __syncthreads(); }
    float inv = 1.f / red[0];
    float* outp = sk + ((size_t)(b * KD + kc)) * MM;
#pragma unroll
    for (int j = 0; j < 4; ++j) outp[tid + j * 256] = e[j] * inv;
}

// ---------------------------------------------------------------------------
// K5: content lambda  (unchanged)
// ---------------------------------------------------------------------------
__global__ __launch_bounds__(256) void k_lamc(
    const float2* __restrict__ O, const float* __restrict__ sk,
    float2* __restrict__ lamc)
{
    int k = blockIdx.x, b = blockIdx.y;
    int tid = threadIdx.x;
    int v = tid >> 3, s = tid & 7;
    const float*  skr  = sk + ((size_t)(b * KD + k)) * MM;
    const float2* vrow = O  + ((size_t)(b * NCH + 144 + v)) * MM;
    float ar = 0.f, ai = 0.f;
    for (int i = 0; i < 128; ++i) {
        int m = s * 128 + i;
        float w = skr[m]; float2 vv = vrow[m];
        ar += w * vv.x; ai += w * vv.y;
    }
    __shared__ float2 part[32][8];
    part[v][s] = make_float2(ar, ai);
    __syncthreads();
    if (tid < 32) {
        float2 t = part[tid][0];
#pragma unroll
        for (int j = 1; j < 8; ++j) { t.x += part[tid][j].x; t.y += part[tid][j].y; }
        lamc[((size_t)(b * KD + k)) * VD + tid] = t;
    }
}

// ---------------------------------------------------------------------------
// k_eprep — repack emb into embC[k][di][dj] = u32( bf16(im)<<16 | bf16(re) )
// ---------------------------------------------------------------------------
__global__ __launch_bounds__(256) void k_eprep(
    const float* __restrict__ er, const float* __restrict__ ei,
    unsigned* __restrict__ embC)
{
    int i = blockIdx.x * 256 + threadIdx.x;
    if (i >= 63 * 63 * 16) return;
    int kk = i & 15;
    int rest = i >> 4;
    int dj = rest % 63;
    int di = rest / 63;
    embC[(kk * 63 + di) * 63 + dj] = bf16rne(er[i]) | (bf16rne(ei[i]) << 16);
}

// ---------------------------------------------------------------------------
// k_vprep — split BN'd V channels of O into bf16 planes VbfR/VbfI[bv][m]
// ---------------------------------------------------------------------------
__global__ __launch_bounds__(256) void k_vprep(
    const float2* __restrict__ O,
    unsigned* __restrict__ VR, unsigned* __restrict__ VI)
{
    int t = blockIdx.x * 256 + threadIdx.x;       // 0..262143
    int bv = t >> 9, mdw = t & 511;
    int b = bv >> 5, v = bv & 31;
    const float2* src = O + ((size_t)(b * NCH + 144 + v)) * MM + mdw * 2;
    float2 a = src[0], c = src[1];
    VR[t] = bf16rne(a.x) | (bf16rne(c.x) << 16);
    VI[t] = bf16rne(a.y) | (bf16rne(c.y) << 16);
}

// ---------------------------------------------------------------------------
// k_main: bf16 MFMA for lam_p, fused lam_c add + q-contraction epilogue.
// R3 fix: epilogue fully unrolled (static acc indexing — the round-2 version
// dynamically indexed accr[g][t], which forced the whole 128-reg accumulator
// array into scratch: 2.4 GB/dispatch of spill traffic, kernel memory-bound).
// lamc loads hoisted out of the g-loop.
// ---------------------------------------------------------------------------
__global__ __launch_bounds__(256, 2) void k_main(
    const float2* __restrict__ O,
    const unsigned* __restrict__ embC,
    const unsigned* __restrict__ VbfR,
    const unsigned* __restrict__ VbfI,
    const float2* __restrict__ lamc,
    float* __restrict__ out, int cplx)
{
    const int tid  = threadIdx.x;
    const int w    = tid >> 6;
    const int lane = tid & 63;
    const int quad = lane >> 4;
    const int col  = lane & 15;

    const int n0  = blockIdx.x * 4;
    const int bvh = blockIdx.y;
    const int b0  = bvh * 8;
    const int ni  = n0 >> 5;
    const int nj0 = n0 & 31;

    __shared__ __align__(16) unsigned shraw[8192];   // V stage (32 KB) / lamt
    unsigned* vsR = shraw;
    unsigned* vsI = shraw + 4096;
    float2*   lamt = (float2*)shraw;                 // [16k][256bv]
    __shared__ __align__(16) float2 qsh[4096];       // [bl(8)][ch(128)][g(4)]

    // stage q tile (BN already applied in place)
#pragma unroll
    for (int it = 0; it < 16; ++it) {
        int idx = it * 256 + tid;
        int g = idx & 3, ch = (idx >> 2) & 127, bl = idx >> 9;
        qsh[idx] = O[((size_t)((b0 + bl) * NCH + ch)) * MM + n0 + g];
    }

    f32x4 accr[4][4], acci[4][4];
#pragma unroll
    for (int g = 0; g < 4; ++g)
#pragma unroll
        for (int t = 0; t < 4; ++t) {
            accr[g][t] = (f32x4){0.f, 0.f, 0.f, 0.f};
            acci[g][t] = (f32x4){0.f, 0.f, 0.f, 0.f};
        }

    const unsigned* vsrcR = VbfR + (size_t)(bvh * 256) * 512;
    const unsigned* vsrcI = VbfI + (size_t)(bvh * 256) * 512;
    const int rowLane = lane >> 2;
    const int moff    = (lane & 3) * 4;

    for (int c = 0; c < 32; ++c) {
        // ---- stage V chunk: wave w stages rows [w*64, w*64+64)
        {
            const unsigned* gR = vsrcR + ((size_t)(w * 64 + rowLane)) * 512 + c * 16 + moff;
            const unsigned* gI = vsrcI + ((size_t)(w * 64 + rowLane)) * 512 + c * 16 + moff;
#pragma unroll
            for (int r16 = 0; r16 < 4; ++r16) {
                GL2LDS16(gR + (size_t)r16 * 16 * 512, vsR + w * 1024 + r16 * 256);
                GL2LDS16(gI + (size_t)r16 * 16 * 512, vsI + w * 1024 + r16 * 256);
            }
        }
        __syncthreads();

        // ---- hoist B-fragments (reused across 4 n)
        short8 Br[4], Bi[4];
#pragma unroll
        for (int t = 0; t < 4; ++t) {
            int rowb = w * 64 + t * 16 + col;
            Br[t] = *(const short8*)&vsR[rowb * 16 + quad * 4];
            Bi[t] = *(const short8*)&vsI[rowb * 16 + quad * 4];
        }

        const int di = c - ni + 31;
#pragma unroll
        for (int g = 0; g < 4; ++g) {
            int dj0 = quad * 8 + 31 - (nj0 + g);
            const unsigned* ap = embC + ((size_t)(col * 63 + di)) * 63 + dj0;
            u32x4a d0 = *(const u32x4a*)ap;
            u32x4a d1 = *(const u32x4a*)(ap + 4);
            union { unsigned u[4]; short8 s; } Rr, Ri, Rin;
            Rr.u[0] = __builtin_amdgcn_perm(d0.y, d0.x, 0x05040100u);
            Rr.u[1] = __builtin_amdgcn_perm(d0.w, d0.z, 0x05040100u);
            Rr.u[2] = __builtin_amdgcn_perm(d1.y, d1.x, 0x05040100u);
            Rr.u[3] = __builtin_amdgcn_perm(d1.w, d1.z, 0x05040100u);
            Ri.u[0] = __builtin_amdgcn_perm(d0.y, d0.x, 0x07060302u);
            Ri.u[1] = __builtin_amdgcn_perm(d0.w, d0.z, 0x07060302u);
            Ri.u[2] = __builtin_amdgcn_perm(d1.y, d1.x, 0x07060302u);
            Ri.u[3] = __builtin_amdgcn_perm(d1.w, d1.z, 0x07060302u);
            Rin.u[0] = Ri.u[0] ^ 0x80008000u;
            Rin.u[1] = Ri.u[1] ^ 0x80008000u;
            Rin.u[2] = Ri.u[2] ^ 0x80008000u;
            Rin.u[3] = Ri.u[3] ^ 0x80008000u;
#pragma unroll
            for (int t = 0; t < 4; ++t) {
                accr[g][t] = __builtin_amdgcn_mfma_f32_16x16x32_bf16(Rr.s,  Br[t], accr[g][t], 0, 0, 0);
                accr[g][t] = __builtin_amdgcn_mfma_f32_16x16x32_bf16(Rin.s, Bi[t], accr[g][t], 0, 0, 0);
                acci[g][t] = __builtin_amdgcn_mfma_f32_16x16x32_bf16(Rr.s,  Bi[t], acci[g][t], 0, 0, 0);
                acci[g][t] = __builtin_amdgcn_mfma_f32_16x16x32_bf16(Ri.s,  Br[t], acci[g][t], 0, 0, 0);
            }
        }
        __syncthreads();
    }

    // ---- hoist lam_c (g-invariant): lcv[t][r]
    float2 lcv[4][4];
#pragma unroll
    for (int t = 0; t < 4; ++t) {
        int bvl = w * 64 + t * 16 + col;
        int bloc = b0 + (bvl >> 5), v = bvl & 31;
#pragma unroll
        for (int r = 0; r < 4; ++r)
            lcv[t][r] = lamc[((size_t)(bloc * KD + quad * 4 + r)) * VD + v];
    }

    // ---- epilogue (FULLY UNROLLED — g must stay a compile-time constant)
    const int blY = tid >> 5, vY = tid & 31;
    const int bY  = b0 + blY;
    float2* op2 = (float2*)out;
#pragma unroll
    for (int g = 0; g < 4; ++g) {
        __syncthreads();
#pragma unroll
        for (int t = 0; t < 4; ++t) {
            int bvl = w * 64 + t * 16 + col;
#pragma unroll
            for (int r = 0; r < 4; ++r) {
                int k = quad * 4 + r;
                lamt[k * 256 + bvl] = make_float2(accr[g][t][r] + lcv[t][r].x,
                                                  acci[g][t][r] + lcv[t][r].y);
            }
        }
        __syncthreads();
        float yr[8], yi[8];
#pragma unroll
        for (int h = 0; h < 8; ++h) { yr[h] = 0.f; yi[h] = 0.f; }
#pragma unroll
        for (int k = 0; k < 16; ++k) {
            float2 l = lamt[k * 256 + tid];
#pragma unroll
            for (int h = 0; h < 8; ++h) {
                float2 q = qsh[(blY * 128 + h * 16 + k) * 4 + g];
                yr[h] += q.x * l.x - q.y * l.y;
                yi[h] += q.x * l.y + q.y * l.x;
            }
        }
        int n = n0 + g;
        if (cplx) {
#pragma unroll
            for (int h = 0; h < 8; ++h)
                op2[((size_t)(bY * 256 + h * 32 + vY)) * MM + n] = make_float2(yr[h], yi[h]);
        } else {
#pragma unroll
            for (int h = 0; h < 8; ++h)
                out[((size_t)(bY * 256 + h * 32 + vY)) * MM + n] = yr[h];
        }
    }
}

// ---------------------------------------------------------------------------
extern "C" void kernel_launch(void* const* d_in, const int* in_sizes, int n_in,
                              void* d_out, int out_size, void* d_ws, size_t ws_size,
                              hipStream_t stream)
{
    const float* x_re  = (const float*)d_in[0];
    const float* x_im  = (const float*)d_in[1];
    const float* wq_re = (const float*)d_in[2];
    const float* wq_im = (const float*)d_in[3];
    const float* wk_re = (const float*)d_in[4];
    const float* wk_im = (const float*)d_in[5];
    const float* wv_re = (const float*)d_in[6];
    const float* wv_im = (const float*)d_in[7];
    const float* qs_re = (const float*)d_in[8];
    const float* qs_im = (const float*)d_in[9];
    const float* qb_re = (const float*)d_in[10];
    const float* qb_im = (const float*)d_in[11];
    const float* vs_re = (const float*)d_in[12];
    const float* vs_im = (const float*)d_in[13];
    const float* vb_re = (const float*)d_in[14];
    const float* vb_im = (const float*)d_in[15];
    const float* emb_re = (const float*)d_in[16];
    const float* emb_im = (const float*)d_in[17];

    float* ws = (float*)d_ws;
    const size_t O_OFF  = 0;                                     // 5,767,168
    const size_t ST_OFF = O_OFF + (size_t)BB * NCH * MM * 2;     // 640
    const size_t SK_OFF = ST_OFF + 640;                          // 262,144
    const size_t LC_OFF = SK_OFF + (size_t)BB * KD * MM;         // 16,384
    const size_t EC_OFF = LC_OFF + 16384;                        // 63,504
    const size_t VR_OFF = EC_OFF + 63504;                        // 262,144
    const size_t VI_OFF = VR_OFF + 262144;                       // 262,144

    float2*   O     = (float2*)(ws + O_OFF);
    float4*   stats = (float4*)(ws + ST_OFF);
    float*    sk    = ws + SK_OFF;
    float2*   lamc  = (float2*)(ws + LC_OFF);
    unsigned* embC  = (unsigned*)(ws + EC_OFF);
    unsigned* VbfR  = (unsigned*)(ws + VR_OFF);
    unsigned* VbfI  = (unsigned*)(ws + VI_OFF);
    float*    outp  = (float*)d_out;

    int cplx = (out_size >= 2 * BB * 256 * MM) ? 1 : 0;

    k_proj<<<dim3(4, 11, BB), 256, 0, stream>>>(x_re, x_im, wq_re, wq_im,
                                                wk_re, wk_im, wv_re, wv_im, O);
    k_eprep<<<dim3(249), 256, 0, stream>>>(emb_re, emb_im, embC);
    k_bnstats<<<dim3(160), 256, 0, stream>>>(O, qs_re, qs_im, qb_re, qb_im,
                                             vs_re, vs_im, vb_re, vb_im, stats);
    k_bnapply<<<dim3(160, BB), 256, 0, stream>>>(stats, O);
    k_softmax<<<dim3(KD, BB), 256, 0, stream>>>(O, sk);
    k_lamc<<<dim3(KD, BB), 256, 0, stream>>>(O, sk, lamc);
    k_vprep<<<dim3(1024), 256, 0, stream>>>(O, VbfR, VbfI);
    k_main<<<dim3(256, 2), 256, 0, stream>>>(O, embC, VbfR, VbfI, lamc, outp, cplx);
}

// Round 4
// 348.923 us; speedup vs baseline: 5.3641x; 1.4785x over previous
//
#include <hip/hip_runtime.h>
#include <math.h>

// Problem constants
#define DIMC 256   // input channels
#define NCH  176   // 128 q + 16 k + 32 v output channels
#define MM   1024  // N2 spatial
#define BB   16    // batch
#define KD   16    // DIM_K
#define HH   8     // heads
#define VD   32    // DIM_V
#define EPSV 1e-5
#define OPAD 192   // padded output channels for MFMA proj (12 o-tiles)

typedef short short8 __attribute__((ext_vector_type(8)));
typedef float f32x4  __attribute__((ext_vector_type(4)));
typedef unsigned u32x4v __attribute__((ext_vector_type(4)));
typedef u32x4v u32x4a __attribute__((aligned(4)));   // 4-byte-aligned dwordx4

union frag8 { unsigned u[4]; short8 s; u32x4v v; };

__device__ __forceinline__ unsigned bf16rne(float f) {
    unsigned u = __float_as_uint(f);
    unsigned r = u + 0x7FFFu + ((u >> 16) & 1u);
    return r >> 16;
}
__device__ __forceinline__ float bf16tof(unsigned h) {
    return __uint_as_float(h << 16);
}

#define GL2LDS16(g, l) __builtin_amdgcn_global_load_lds( \
    (const __attribute__((address_space(1))) unsigned*)(g), \
    (__attribute__((address_space(3))) unsigned*)(l), 16, 0, 0)

// ---------------------------------------------------------------------------
// k_wprep: pack W (q|k|v concat, padded to 192 rows) into 4 planes of
// [192][128] u32, each u32 = bf16(c odd)<<16 | bf16(c even):
//   plane 0 = re_hi, 1 = im_hi, 2 = re_lo, 3 = im_lo  (hi/lo split-bf16)
// ---------------------------------------------------------------------------
__global__ __launch_bounds__(256) void k_wprep(
    const float* __restrict__ wq_re, const float* __restrict__ wq_im,
    const float* __restrict__ wk_re, const float* __restrict__ wk_im,
    const float* __restrict__ wv_re, const float* __restrict__ wv_im,
    unsigned* __restrict__ Wpk)
{
    int idx = blockIdx.x * 256 + threadIdx.x;   // 0..24575
    if (idx >= OPAD * 128) return;
    int o = idx >> 7, j = idx & 127;
    int c0 = 2 * j;
    float r0 = 0.f, r1 = 0.f, i0 = 0.f, i1 = 0.f;
    if (o < 128) {
        r0 = wq_re[o * DIMC + c0]; r1 = wq_re[o * DIMC + c0 + 1];
        i0 = wq_im[o * DIMC + c0]; i1 = wq_im[o * DIMC + c0 + 1];
    } else if (o < 144) {
        int oo = o - 128;
        r0 = wk_re[oo * DIMC + c0]; r1 = wk_re[oo * DIMC + c0 + 1];
        i0 = wk_im[oo * DIMC + c0]; i1 = wk_im[oo * DIMC + c0 + 1];
    } else if (o < 176) {
        int oo = o - 144;
        r0 = wv_re[oo * DIMC + c0]; r1 = wv_re[oo * DIMC + c0 + 1];
        i0 = wv_im[oo * DIMC + c0]; i1 = wv_im[oo * DIMC + c0 + 1];
    }
    unsigned rh0 = bf16rne(r0), rh1 = bf16rne(r1);
    unsigned ih0 = bf16rne(i0), ih1 = bf16rne(i1);
    float rl0 = r0 - bf16tof(rh0), rl1 = r1 - bf16tof(rh1);
    float il0 = i0 - bf16tof(ih0), il1 = i1 - bf16tof(ih1);
    Wpk[0 * OPAD * 128 + idx] = rh0 | (rh1 << 16);
    Wpk[1 * OPAD * 128 + idx] = ih0 | (ih1 << 16);
    Wpk[2 * OPAD * 128 + idx] = bf16rne(rl0) | (bf16rne(rl1) << 16);
    Wpk[3 * OPAD * 128 + idx] = bf16rne(il0) | (bf16rne(il1) << 16);
}

// ---------------------------------------------------------------------------
// k_proj (R4: MFMA): O[b][o][m] = sum_c W[o][c]*X[b][c][m], complex, computed
// with split-bf16 (3-term: hi*hi + hi*lo + lo*hi) => ~fp32 accuracy.
// Block: 256 thr = 4 waves; tile = 192 o x 32 m; grid = (32 m-chunks, 16 b).
// Wave w: m-tile = w&1, o-group = w>>1 (6 o-tiles each). K-loop: 8 x 32 c.
// ---------------------------------------------------------------------------
__global__ __launch_bounds__(256, 2) void k_proj(
    const float* __restrict__ x_re, const float* __restrict__ x_im,
    const unsigned* __restrict__ Wpk,
    float2* __restrict__ O)
{
    const int m0  = blockIdx.x * 32;
    const int b   = blockIdx.y;
    const int tid = threadIdx.x;
    const int w    = tid >> 6;
    const int lane = tid & 63;
    const int quad = lane >> 4;
    const int col  = lane & 15;
    const int mt = w & 1, og = w >> 1;

    __shared__ __align__(16) unsigned Wsh[4 * OPAD * 16];  // 48 KB
    __shared__ __align__(16) unsigned Xsh[4 * 32 * 20];    // 10 KB ([pl][m][16cp+4pad])

    f32x4 accR[6], accI[6];
#pragma unroll
    for (int t = 0; t < 6; ++t) {
        accR[t] = (f32x4){0.f, 0.f, 0.f, 0.f};
        accI[t] = (f32x4){0.f, 0.f, 0.f, 0.f};
    }

    const int ms = tid & 31;           // staging m
    const int cps = tid >> 5;          // staging c-pair base (0..7)

    for (int kk = 0; kk < 8; ++kk) {
        // ---- stage W chunk: 4 planes x [192][16] u32
#pragma unroll
        for (int p = 0; p < 12; ++p) {
            int idx = p * 256 + tid;               // dwordx4 id 0..3071
            int plane = idx / 768;
            int rem = idx - plane * 768;
            int row = rem >> 2, seg = rem & 3;
            u32x4v d = *(const u32x4v*)&Wpk[(size_t)plane * (OPAD * 128) + row * 128 + kk * 16 + seg * 4];
            *(u32x4v*)&Wsh[(plane * OPAD + row) * 16 + seg * 4] = d;
        }
        // ---- stage X chunk: 32 c x 32 m, transposed + hi/lo split
#pragma unroll
        for (int p = 0; p < 2; ++p) {
            int cp = cps + p * 8;                  // c-pair 0..15 in chunk
            int c  = kk * 32 + cp * 2;
            size_t base = ((size_t)(b * DIMC + c)) * MM + m0 + ms;
            float r0 = x_re[base],      i0 = x_im[base];
            float r1 = x_re[base + MM], i1 = x_im[base + MM];
            unsigned rh0 = bf16rne(r0), rh1 = bf16rne(r1);
            unsigned ih0 = bf16rne(i0), ih1 = bf16rne(i1);
            float rl0 = r0 - bf16tof(rh0), rl1 = r1 - bf16tof(rh1);
            float il0 = i0 - bf16tof(ih0), il1 = i1 - bf16tof(ih1);
            Xsh[0 * 640 + ms * 20 + cp] = rh0 | (rh1 << 16);
            Xsh[1 * 640 + ms * 20 + cp] = ih0 | (ih1 << 16);
            Xsh[2 * 640 + ms * 20 + cp] = bf16rne(rl0) | (bf16rne(rl1) << 16);
            Xsh[3 * 640 + ms * 20 + cp] = bf16rne(il0) | (bf16rne(il1) << 16);
        }
        __syncthreads();

        // ---- B-fragments (fixed m-tile per wave, reused over 6 o-tiles)
        int mrow = mt * 16 + col;
        short8 Xrh = *(const short8*)&Xsh[0 * 640 + mrow * 20 + quad * 4];
        short8 Xih = *(const short8*)&Xsh[1 * 640 + mrow * 20 + quad * 4];
        short8 Xrl = *(const short8*)&Xsh[2 * 640 + mrow * 20 + quad * 4];
        short8 Xil = *(const short8*)&Xsh[3 * 640 + mrow * 20 + quad * 4];

#pragma unroll
        for (int ot = 0; ot < 6; ++ot) {
            int orow = (og * 6 + ot) * 16 + col;
            frag8 Arh, Aih, Arl, Ail, Anh, Anl;
            Arh.s = *(const short8*)&Wsh[(0 * OPAD + orow) * 16 + quad * 4];
            Aih.s = *(const short8*)&Wsh[(1 * OPAD + orow) * 16 + quad * 4];
            Arl.s = *(const short8*)&Wsh[(2 * OPAD + orow) * 16 + quad * 4];
            Ail.s = *(const short8*)&Wsh[(3 * OPAD + orow) * 16 + quad * 4];
#pragma unroll
            for (int i = 0; i < 4; ++i) {
                Anh.u[i] = Aih.u[i] ^ 0x80008000u;
                Anl.u[i] = Ail.u[i] ^ 0x80008000u;
            }
            // accR += Wr*Xr - Wi*Xi  (hi*hi + hi*lo + lo*hi)
            accR[ot] = __builtin_amdgcn_mfma_f32_16x16x32_bf16(Arh.s, Xrh, accR[ot], 0, 0, 0);
            accR[ot] = __builtin_amdgcn_mfma_f32_16x16x32_bf16(Anh.s, Xih, accR[ot], 0, 0, 0);
            accR[ot] = __builtin_amdgcn_mfma_f32_16x16x32_bf16(Arh.s, Xrl, accR[ot], 0, 0, 0);
            accR[ot] = __builtin_amdgcn_mfma_f32_16x16x32_bf16(Anh.s, Xil, accR[ot], 0, 0, 0);
            accR[ot] = __builtin_amdgcn_mfma_f32_16x16x32_bf16(Arl.s, Xrh, accR[ot], 0, 0, 0);
            accR[ot] = __builtin_amdgcn_mfma_f32_16x16x32_bf16(Anl.s, Xih, accR[ot], 0, 0, 0);
            // accI += Wr*Xi + Wi*Xr
            accI[ot] = __builtin_amdgcn_mfma_f32_16x16x32_bf16(Arh.s, Xih, accI[ot], 0, 0, 0);
            accI[ot] = __builtin_amdgcn_mfma_f32_16x16x32_bf16(Aih.s, Xrh, accI[ot], 0, 0, 0);
            accI[ot] = __builtin_amdgcn_mfma_f32_16x16x32_bf16(Arh.s, Xil, accI[ot], 0, 0, 0);
            accI[ot] = __builtin_amdgcn_mfma_f32_16x16x32_bf16(Aih.s, Xrl, accI[ot], 0, 0, 0);
            accI[ot] = __builtin_amdgcn_mfma_f32_16x16x32_bf16(Arl.s, Xih, accI[ot], 0, 0, 0);
            accI[ot] = __builtin_amdgcn_mfma_f32_16x16x32_bf16(Ail.s, Xrh, accI[ot], 0, 0, 0);
        }
        __syncthreads();
    }

    // ---- epilogue: store (skip padded o-tile 11)
#pragma unroll
    for (int ot = 0; ot < 6; ++ot) {
        int gto = og * 6 + ot;
        if (gto >= 11) continue;
#pragma unroll
        for (int r = 0; r < 4; ++r) {
            int o = gto * 16 + quad * 4 + r;
            O[((size_t)(b * NCH + o)) * MM + m0 + mt * 16 + col] =
                make_float2(accR[ot][r], accI[ot][r]);
        }
    }
}

// ---------------------------------------------------------------------------
// K2: complex BN stats (double accumulation), folds to affine A,B  (unchanged)
// ---------------------------------------------------------------------------
__global__ __launch_bounds__(256) void k_bnstats(
    const float2* __restrict__ O,
    const float* __restrict__ qs_re, const float* __restrict__ qs_im,
    const float* __restrict__ qb_re, const float* __restrict__ qb_im,
    const float* __restrict__ vs_re, const float* __restrict__ vs_im,
    const float* __restrict__ vb_re, const float* __restrict__ vb_im,
    float4* __restrict__ stats)
{
    const int ch  = blockIdx.x;
    const int o   = (ch < 128) ? ch : (144 + ch - 128);
    const int tid = threadIdx.x;

    double sr = 0, si = 0, sq = 0, sri = 0;
    for (int idx = tid; idx < BB * MM; idx += 256) {
        int b = idx >> 10, m = idx & 1023;
        float2 val = O[((size_t)(b * NCH + o)) * MM + m];
        double r = val.x, ii = val.y;
        sr += r; si += ii; sq += r * r - ii * ii; sri += r * ii;
    }
    __shared__ double red[4][256];
    red[0][tid] = sr; red[1][tid] = si; red[2][tid] = sq; red[3][tid] = sri;
    __syncthreads();
    for (int s = 128; s > 0; s >>= 1) {
        if (tid < s) {
            red[0][tid] += red[0][tid + s]; red[1][tid] += red[1][tid + s];
            red[2][tid] += red[2][tid + s]; red[3][tid] += red[3][tid + s];
        }
        __syncthreads();
    }
    if (tid == 0) {
        const double inv = 1.0 / (double)(BB * MM);
        double mr = red[0][0] * inv, mi = red[1][0] * inv;
        double vr = red[2][0] * inv - (mr * mr - mi * mi) + EPSV;
        double vi = 2.0 * (red[3][0] * inv - mr * mi);
        double rad = sqrt(vr * vr + vi * vi);
        double wr  = sqrt(fmax(0.5 * (rad + vr), 0.0));
        double wi  = sqrt(fmax(0.5 * (rad - vr), 0.0));
        if (vi < 0) wi = -wi;
        double den = wr * wr + wi * wi;
        double ivr = wr / den, ivi = -wi / den;
        double scr, sci, shr, shi;
        if (ch < 128) { scr = qs_re[ch]; sci = qs_im[ch]; shr = qb_re[ch]; shi = qb_im[ch]; }
        else { int i2 = ch - 128; scr = vs_re[i2]; sci = vs_im[i2]; shr = vb_re[i2]; shi = vb_im[i2]; }
        double Ar = scr * ivr - sci * ivi;
        double Ai = scr * ivi + sci * ivr;
        double Br = shr - (Ar * mr - Ai * mi);
        double Bi = shi - (Ar * mi + Ai * mr);
        stats[ch] = make_float4((float)Ar, (float)Ai, (float)Br, (float)Bi);
    }
}

// ---------------------------------------------------------------------------
// K3a: apply BN affine in place; for v channels also emit bf16 planes
// (fused k_vprep).
// ---------------------------------------------------------------------------
__global__ __launch_bounds__(256) void k_bnapply(
    const float4* __restrict__ stats, float2* __restrict__ O,
    unsigned* __restrict__ VR, unsigned* __restrict__ VI)
{
    int ch = blockIdx.x, b = blockIdx.y;
    int o  = (ch < 128) ? ch : (144 + ch - 128);
    float4 s = stats[ch];
    float2* row = O + ((size_t)(b * NCH + o)) * MM;
    int tid = threadIdx.x;
    for (int mm = tid; mm < 512; mm += 256) {
        float4 two = *(float4*)&row[2 * mm];
        float nr0 = s.x * two.x - s.y * two.y + s.z;
        float ni0 = s.x * two.y + s.y * two.x + s.w;
        float nr1 = s.x * two.z - s.y * two.w + s.z;
        float ni1 = s.x * two.w + s.y * two.z + s.w;
        *(float4*)&row[2 * mm] = make_float4(nr0, ni0, nr1, ni1);
        if (ch >= 128) {
            int bv = b * VD + (ch - 128);
            VR[(size_t)bv * 512 + mm] = bf16rne(nr0) | (bf16rne(nr1) << 16);
            VI[(size_t)bv * 512 + mm] = bf16rne(ni0) | (bf16rne(ni1) << 16);
        }
    }
}

// ---------------------------------------------------------------------------
// k_softlam: softmax over m of |k| fused with content lambda
// lam_c[b][k][v] = sum_m softmax(|k|)[m] * Vn[b,v,m]
// ---------------------------------------------------------------------------
__global__ __launch_bounds__(256) void k_softlam(
    const float2* __restrict__ O, float2* __restrict__ lamc)
{
    int kc = blockIdx.x, b = blockIdx.y;
    const float2* row = O + ((size_t)(b * NCH + 128 + kc)) * MM;
    int tid = threadIdx.x;
    __shared__ float red[256];
    __shared__ float skl[1024];

    float mag[4]; float mx = -1e30f;
#pragma unroll
    for (int j = 0; j < 4; ++j) {
        float2 v = row[tid + j * 256];
        mag[j] = sqrtf(v.x * v.x + v.y * v.y);
        mx = fmaxf(mx, mag[j]);
    }
    red[tid] = mx; __syncthreads();
    for (int s = 128; s > 0; s >>= 1) { if (tid < s) red[tid] = fmaxf(red[tid], red[tid + s]); __syncthreads(); }
    mx = red[0]; __syncthreads();
    float e[4]; float sum = 0.f;
#pragma unroll
    for (int j = 0; j < 4; ++j) { e[j] = expf(mag[j] - mx); sum += e[j]; }
    red[tid] = sum; __syncthreads();
    for (int s = 128; s > 0; s >>= 1) { if (tid < s) red[tid] += red[tid + s]; __syncthreads(); }
    float inv = 1.f / red[0];
#pragma unroll
    for (int j = 0; j < 4; ++j) skl[tid + j * 256] = e[j] * inv;
    __syncthreads();

    int v = tid >> 3, s8 = tid & 7;
    const float2* vrow = O + ((size_t)(b * NCH + 144 + v)) * MM;
    float ar = 0.f, ai = 0.f;
    for (int i = 0; i < 128; ++i) {
        int m = s8 * 128 + i;
        float wgt = skl[m]; float2 vv = vrow[m];
        ar += wgt * vv.x; ai += wgt * vv.y;
    }
    __shared__ float2 part[32][8];
    part[v][s8] = make_float2(ar, ai);
    __syncthreads();
    if (tid < 32) {
        float2 t = part[tid][0];
#pragma unroll
        for (int j = 1; j < 8; ++j) { t.x += part[tid][j].x; t.y += part[tid][j].y; }
        lamc[((size_t)(b * KD + kc)) * VD + tid] = t;
    }
}

// ---------------------------------------------------------------------------
// k_eprep — repack emb into embC[k][di][dj] = u32( bf16(im)<<16 | bf16(re) )
// ---------------------------------------------------------------------------
__global__ __launch_bounds__(256) void k_eprep(
    const float* __restrict__ er, const float* __restrict__ ei,
    unsigned* __restrict__ embC)
{
    int i = blockIdx.x * 256 + threadIdx.x;
    if (i >= 63 * 63 * 16) return;
    int kk = i & 15;
    int rest = i >> 4;
    int dj = rest % 63;
    int di = rest / 63;
    embC[(kk * 63 + di) * 63 + dj] = bf16rne(er[i]) | (bf16rne(ei[i]) << 16);
}

// ---------------------------------------------------------------------------
// k_main: bf16 MFMA for lam_p, fused lam_c add + q-contraction epilogue.
// (unchanged from R3 — fully-unrolled epilogue, no scratch spill)
// ---------------------------------------------------------------------------
__global__ __launch_bounds__(256, 2) void k_main(
    const float2* __restrict__ O,
    const unsigned* __restrict__ embC,
    const unsigned* __restrict__ VbfR,
    const unsigned* __restrict__ VbfI,
    const float2* __restrict__ lamc,
    float* __restrict__ out, int cplx)
{
    const int tid  = threadIdx.x;
    const int w    = tid >> 6;
    const int lane = tid & 63;
    const int quad = lane >> 4;
    const int col  = lane & 15;

    const int n0  = blockIdx.x * 4;
    const int bvh = blockIdx.y;
    const int b0  = bvh * 8;
    const int ni  = n0 >> 5;
    const int nj0 = n0 & 31;

    __shared__ __align__(16) unsigned shraw[8192];   // V stage (32 KB) / lamt
    unsigned* vsR = shraw;
    unsigned* vsI = shraw + 4096;
    float2*   lamt = (float2*)shraw;                 // [16k][256bv]
    __shared__ __align__(16) float2 qsh[4096];       // [bl(8)][ch(128)][g(4)]

#pragma unroll
    for (int it = 0; it < 16; ++it) {
        int idx = it * 256 + tid;
        int g = idx & 3, ch = (idx >> 2) & 127, bl = idx >> 9;
        qsh[idx] = O[((size_t)((b0 + bl) * NCH + ch)) * MM + n0 + g];
    }

    f32x4 accr[4][4], acci[4][4];
#pragma unroll
    for (int g = 0; g < 4; ++g)
#pragma unroll
        for (int t = 0; t < 4; ++t) {
            accr[g][t] = (f32x4){0.f, 0.f, 0.f, 0.f};
            acci[g][t] = (f32x4){0.f, 0.f, 0.f, 0.f};
        }

    const unsigned* vsrcR = VbfR + (size_t)(bvh * 256) * 512;
    const unsigned* vsrcI = VbfI + (size_t)(bvh * 256) * 512;
    const int rowLane = lane >> 2;
    const int moff    = (lane & 3) * 4;

    for (int c = 0; c < 32; ++c) {
        {
            const unsigned* gR = vsrcR + ((size_t)(w * 64 + rowLane)) * 512 + c * 16 + moff;
            const unsigned* gI = vsrcI + ((size_t)(w * 64 + rowLane)) * 512 + c * 16 + moff;
#pragma unroll
            for (int r16 = 0; r16 < 4; ++r16) {
                GL2LDS16(gR + (size_t)r16 * 16 * 512, vsR + w * 1024 + r16 * 256);
                GL2LDS16(gI + (size_t)r16 * 16 * 512, vsI + w * 1024 + r16 * 256);
            }
        }
        __syncthreads();

        short8 Br[4], Bi[4];
#pragma unroll
        for (int t = 0; t < 4; ++t) {
            int rowb = w * 64 + t * 16 + col;
            Br[t] = *(const short8*)&vsR[rowb * 16 + quad * 4];
            Bi[t] = *(const short8*)&vsI[rowb * 16 + quad * 4];
        }

        const int di = c - ni + 31;
#pragma unroll
        for (int g = 0; g < 4; ++g) {
            int dj0 = quad * 8 + 31 - (nj0 + g);
            const unsigned* ap = embC + ((size_t)(col * 63 + di)) * 63 + dj0;
            u32x4a d0 = *(const u32x4a*)ap;
            u32x4a d1 = *(const u32x4a*)(ap + 4);
            union { unsigned u[4]; short8 s; } Rr, Ri, Rin;
            Rr.u[0] = __builtin_amdgcn_perm(d0.y, d0.x, 0x05040100u);
            Rr.u[1] = __builtin_amdgcn_perm(d0.w, d0.z, 0x05040100u);
            Rr.u[2] = __builtin_amdgcn_perm(d1.y, d1.x, 0x05040100u);
            Rr.u[3] = __builtin_amdgcn_perm(d1.w, d1.z, 0x05040100u);
            Ri.u[0] = __builtin_amdgcn_perm(d0.y, d0.x, 0x07060302u);
            Ri.u[1] = __builtin_amdgcn_perm(d0.w, d0.z, 0x07060302u);
            Ri.u[2] = __builtin_amdgcn_perm(d1.y, d1.x, 0x07060302u);
            Ri.u[3] = __builtin_amdgcn_perm(d1.w, d1.z, 0x07060302u);
            Rin.u[0] = Ri.u[0] ^ 0x80008000u;
            Rin.u[1] = Ri.u[1] ^ 0x80008000u;
            Rin.u[2] = Ri.u[2] ^ 0x80008000u;
            Rin.u[3] = Ri.u[3] ^ 0x80008000u;
#pragma unroll
            for (int t = 0; t < 4; ++t) {
                accr[g][t] = __builtin_amdgcn_mfma_f32_16x16x32_bf16(Rr.s,  Br[t], accr[g][t], 0, 0, 0);
                accr[g][t] = __builtin_amdgcn_mfma_f32_16x16x32_bf16(Rin.s, Bi[t], accr[g][t], 0, 0, 0);
                acci[g][t] = __builtin_amdgcn_mfma_f32_16x16x32_bf16(Rr.s,  Bi[t], acci[g][t], 0, 0, 0);
                acci[g][t] = __builtin_amdgcn_mfma_f32_16x16x32_bf16(Ri.s,  Br[t], acci[g][t], 0, 0, 0);
            }
        }
        __syncthreads();
    }

    float2 lcv[4][4];
#pragma unroll
    for (int t = 0; t < 4; ++t) {
        int bvl = w * 64 + t * 16 + col;
        int bloc = b0 + (bvl >> 5), v = bvl & 31;
#pragma unroll
        for (int r = 0; r < 4; ++r)
            lcv[t][r] = lamc[((size_t)(bloc * KD + quad * 4 + r)) * VD + v];
    }

    const int blY = tid >> 5, vY = tid & 31;
    const int bY  = b0 + blY;
    float2* op2 = (float2*)out;
#pragma unroll
    for (int g = 0; g < 4; ++g) {
        __syncthreads();
#pragma unroll
        for (int t = 0; t < 4; ++t) {
            int bvl = w * 64 + t * 16 + col;
#pragma unroll
            for (int r = 0; r < 4; ++r) {
                int k = quad * 4 + r;
                lamt[k * 256 + bvl] = make_float2(accr[g][t][r] + lcv[t][r].x,
                                                  acci[g][t][r] + lcv[t][r].y);
            }
        }
        __syncthreads();
        float yr[8], yi[8];
#pragma unroll
        for (int h = 0; h < 8; ++h) { yr[h] = 0.f; yi[h] = 0.f; }
#pragma unroll
        for (int k = 0; k < 16; ++k) {
            float2 l = lamt[k * 256 + tid];
#pragma unroll
            for (int h = 0; h < 8; ++h) {
                float2 q = qsh[(blY * 128 + h * 16 + k) * 4 + g];
                yr[h] += q.x * l.x - q.y * l.y;
                yi[h] += q.x * l.y + q.y * l.x;
            }
        }
        int n = n0 + g;
        if (cplx) {
#pragma unroll
            for (int h = 0; h < 8; ++h)
                op2[((size_t)(bY * 256 + h * 32 + vY)) * MM + n] = make_float2(yr[h], yi[h]);
        } else {
#pragma unroll
            for (int h = 0; h < 8; ++h)
                out[((size_t)(bY * 256 + h * 32 + vY)) * MM + n] = yr[h];
        }
    }
}

// ---------------------------------------------------------------------------
extern "C" void kernel_launch(void* const* d_in, const int* in_sizes, int n_in,
                              void* d_out, int out_size, void* d_ws, size_t ws_size,
                              hipStream_t stream)
{
    const float* x_re  = (const float*)d_in[0];
    const float* x_im  = (const float*)d_in[1];
    const float* wq_re = (const float*)d_in[2];
    const float* wq_im = (const float*)d_in[3];
    const float* wk_re = (const float*)d_in[4];
    const float* wk_im = (const float*)d_in[5];
    const float* wv_re = (const float*)d_in[6];
    const float* wv_im = (const float*)d_in[7];
    const float* qs_re = (const float*)d_in[8];
    const float* qs_im = (const float*)d_in[9];
    const float* qb_re = (const float*)d_in[10];
    const float* qb_im = (const float*)d_in[11];
    const float* vs_re = (const float*)d_in[12];
    const float* vs_im = (const float*)d_in[13];
    const float* vb_re = (const float*)d_in[14];
    const float* vb_im = (const float*)d_in[15];
    const float* emb_re = (const float*)d_in[16];
    const float* emb_im = (const float*)d_in[17];

    float* ws = (float*)d_ws;
    const size_t O_OFF  = 0;                                     // 5,767,168
    const size_t ST_OFF = O_OFF + (size_t)BB * NCH * MM * 2;     // 640
    const size_t LC_OFF = ST_OFF + 640;                          // 16,384
    const size_t EC_OFF = LC_OFF + 16384;                        // 63,504
    const size_t WP_OFF = EC_OFF + 63504;                        // 98,304 (Wpk)
    const size_t VR_OFF = WP_OFF + 98304;                        // 262,144
    const size_t VI_OFF = VR_OFF + 262144;                       // 262,144

    float2*   O     = (float2*)(ws + O_OFF);
    float4*   stats = (float4*)(ws + ST_OFF);
    float2*   lamc  = (float2*)(ws + LC_OFF);
    unsigned* embC  = (unsigned*)(ws + EC_OFF);
    unsigned* Wpk   = (unsigned*)(ws + WP_OFF);
    unsigned* VbfR  = (unsigned*)(ws + VR_OFF);
    unsigned* VbfI  = (unsigned*)(ws + VI_OFF);
    float*    outp  = (float*)d_out;

    int cplx = (out_size >= 2 * BB * 256 * MM) ? 1 : 0;

    k_wprep<<<dim3(96), 256, 0, stream>>>(wq_re, wq_im, wk_re, wk_im,
                                          wv_re, wv_im, Wpk);
    k_eprep<<<dim3(249), 256, 0, stream>>>(emb_re, emb_im, embC);
    k_proj<<<dim3(32, BB), 256, 0, stream>>>(x_re, x_im, Wpk, O);
    k_bnstats<<<dim3(160), 256, 0, stream>>>(O, qs_re, qs_im, qb_re, qb_im,
                                             vs_re, vs_im, vb_re, vb_im, stats);
    k_bnapply<<<dim3(160, BB), 256, 0, stream>>>(stats, O, VbfR, VbfI);
    k_softlam<<<dim3(KD, BB), 256, 0, stream>>>(O, lamc);
    k_main<<<dim3(256, 2), 256, 0, stream>>>(O, embC, VbfR, VbfI, lamc, outp, cplx);
}